// Round 6
// baseline (236.341 us; speedup 1.0000x reference)
//
#include <hip/hip_runtime.h>

#define BB 4
#define CC 32
#define HH 480
#define WW 640
#define HWv (HH*WW)

// ---- conv tiling: 4 rows x 64 cols per block, 64 threads (1 wave), 4 px/thread
#define TR 4
#define TC 64
#define FR 6        // TR + 2 halo rows
#define FC 72       // TC + 8 (4-aligned halo cols: x0-4 .. x0+67)
#define BUFF 512    // staged floats per buffer (2 issues x 256 >= FR*FC=432)

// ---------------------------------------------------------------------------
// Kernel 1: 3x3 conv (32->8) + bias + affinity normalization.
// One wave per block -> barrier-free channel pipeline:
//   vmcnt(0) -> stage(c+1) -> ds_read rows(c) -> FMA(c)
// vmcnt(0)-at-top is count-pollution-immune (R4 lesson); latency hiding
// comes from occupancy: 4800 blocks ~ 4.7 waves/SIMD.
// Halo via __shfl from neighbor lanes (conflict-free); only tx==0/15 lanes
// touch LDS scalars (4 lanes, distinct banks).
// ---------------------------------------------------------------------------
__global__ __launch_bounds__(64, 6) void conv_gen(const float* __restrict__ kx,
                                                  const float* __restrict__ Wf,
                                                  const float* __restrict__ bf,
                                                  float* __restrict__ K)
{
    __shared__ float lds[2 * BUFF];    // 4 KB

    const int t  = threadIdx.x;        // 0..63 (= lane)
    const int tx = t & 15;             // 0..15  (4-px column group)
    const int ty = t >> 4;             // 0..3   (row in tile)

    int blk = blockIdx.x;
    const int xt = blk % (WW / TC); blk /= (WW / TC);
    const int yt = blk % (HH / TR);
    const int b  = blk / (HH / TR);
    const int y0 = yt * TR;
    const int x0 = xt * TC;

    const float* kxb = kx + (size_t)b * CC * HWv;

    // ---- per-lane clamped source offsets for the 2 staging issues ----
    int srcoff[2];
#pragma unroll
    for (int j = 0; j < 2; ++j) {
        int f  = j * 256 + t * 4;         // flat float index in fetch region
        int fr = f / FC;
        int fc = f - fr * FC;             // multiple of 4
        int rg = y0 - 1 + fr; rg = rg < 0 ? 0 : (rg > HH - 1 ? HH - 1 : rg);
        int cg = x0 - 4 + fc; cg = cg < 0 ? 0 : (cg > WW - 4 ? WW - 4 : cg);
        srcoff[j] = rg * WW + cg;
    }

    // ---- channel-invariant boundary masks ----
    const float xmf = (x0 + 4 * tx     > 0 ) ? 1.f : 0.f;   // left halo valid
    const float xpf = (x0 + 4 * tx + 4 < WW) ? 1.f : 0.f;   // right halo valid
    float ml0[3], mc0[3], mr0[3];
#pragma unroll
    for (int r = 0; r < 3; ++r) {
        int ry = y0 + ty + r - 1;
        float ok = (ry >= 0 && ry < HH) ? 1.f : 0.f;
        mc0[r] = ok; ml0[r] = ok * xmf; mr0[r] = ok * xpf;
    }

    float acc[8][4];
#pragma unroll
    for (int o = 0; o < 8; ++o) {
        float bv = bf[o];
#pragma unroll
        for (int p = 0; p < 4; ++p) acc[o][p] = bv;
    }

    // ---- async stage: 2 global_load_lds (width 16) per channel ----
    auto stage = [&](int c, int buf) {
        const float* src = kxb + (size_t)c * HWv;
#pragma unroll
        for (int j = 0; j < 2; ++j) {
            float* dst = &lds[buf * BUFF + j * 256];
            __builtin_amdgcn_global_load_lds(
                (const __attribute__((address_space(1))) void*)(src + srcoff[j]),
                (__attribute__((address_space(3))) void*)dst, 16, 0, 0);
        }
    };

    stage(0, 0);

#pragma unroll 1
    for (int c = 0; c < CC; ++c) {
        // drain: buf[c&1] complete (safe regardless of other vmem in queue)
        asm volatile("s_waitcnt vmcnt(0)" ::: "memory");
        __builtin_amdgcn_sched_barrier(0);

        if (c + 1 < CC) stage(c + 1, (c + 1) & 1);   // prefetch under FMAs

        const float* bufp = &lds[(c & 1) * BUFF];
        float rowv[3][6];
#pragma unroll
        for (int r = 0; r < 3; ++r) {
            // window = fetched cols 4tx+3 .. 4tx+8 (global x-1 .. x+4)
            const float* rp = bufp + (ty + r) * FC + 4 * tx + 3;
            float4 va = *reinterpret_cast<const float4*>(rp + 1);  // 16B-aligned
            float lv = __shfl_up(va.w, 1);      // neighbor's col x-1
            if (tx == 0)  lv = rp[0];           // tile-edge: LDS scalar
            float rv = __shfl_down(va.x, 1);    // neighbor's col x+4
            if (tx == 15) rv = rp[5];
            rowv[r][0] = lv   * ml0[r];
            rowv[r][1] = va.x * mc0[r]; rowv[r][2] = va.y * mc0[r];
            rowv[r][3] = va.z * mc0[r]; rowv[r][4] = va.w * mc0[r];
            rowv[r][5] = rv   * mr0[r];
        }

        const float* wc = Wf + c * 9;
#pragma unroll
        for (int o = 0; o < 8; ++o) {
#pragma unroll
            for (int r = 0; r < 3; ++r) {
#pragma unroll
                for (int s = 0; s < 3; ++s) {
                    float wvv = wc[o * (CC * 9) + r * 3 + s];  // uniform -> s_load
#pragma unroll
                    for (int p = 0; p < 4; ++p) acc[o][p] += wvv * rowv[r][p + s];
                }
            }
        }
    }

    // ---- normalization: a = aff / sum|aff|; K0 = 1 - sum(a) ----
    float k0[4];
#pragma unroll
    for (int p = 0; p < 4; ++p) {
        float asum = 0.f;
#pragma unroll
        for (int o = 0; o < 8; ++o) asum += fabsf(acc[o][p]);
        float rinv = 1.0f / asum;
        float s = 0.f;
#pragma unroll
        for (int o = 0; o < 8; ++o) { acc[o][p] *= rinv; s += acc[o][p]; }
        k0[p] = 1.0f - s;
    }

    size_t base = (size_t)b * 9 * HWv + (size_t)(y0 + ty) * WW + x0 + 4 * tx;
    *reinterpret_cast<float4*>(K + base) = make_float4(k0[0], k0[1], k0[2], k0[3]);
#pragma unroll
    for (int o = 0; o < 8; ++o) {
        *reinterpret_cast<float4*>(K + base + (size_t)(o + 1) * HWv) =
            make_float4(acc[o][0], acc[o][1], acc[o][2], acc[o][3]);
    }
}

// ---------------------------------------------------------------------------
// Kernel 2: one propagation iteration (unchanged).
// OFFSETS order: (0,0),(0,1),(0,-1),(1,0),(1,1),(1,-1),(-1,0),(-1,1),(-1,-1)
// ---------------------------------------------------------------------------
__device__ __forceinline__ void load_row6(const float* r, bool rowok, bool xm,
                                          bool xpl, float o[6])
{
    if (rowok) {
        float4 v = *reinterpret_cast<const float4*>(r);
        o[0] = xm ? r[-1] : 0.f;
        o[1] = v.x; o[2] = v.y; o[3] = v.z; o[4] = v.w;
        o[5] = xpl ? r[4] : 0.f;
    } else {
#pragma unroll
        for (int q = 0; q < 6; ++q) o[q] = 0.f;
    }
}

__global__ __launch_bounds__(256) void prop(const float* __restrict__ xin,
                                            const float* __restrict__ K,
                                            float* __restrict__ xout)
{
    int tid = blockIdx.x * 256 + threadIdx.x;
    const int XT = WW / 4;
    int x4 = tid % XT;
    int t2 = tid / XT;
    int y  = t2 % HH;
    int b  = t2 / HH;
    if (b >= BB) return;
    int x0 = x4 * 4;

    const bool xm  = (x0 > 0);
    const bool xpl = (x0 + 4 < WW);

    const float* xb = xin + (size_t)b * HWv + (size_t)y * WW + x0;
    float rm[6], r0[6], rp[6];
    load_row6(xb - WW, y > 0,      xm, xpl, rm);
    load_row6(xb,      true,       xm, xpl, r0);
    load_row6(xb + WW, y < HH - 1, xm, xpl, rp);

    const float* Kb = K + (size_t)b * 9 * HWv + (size_t)y * WW + x0;
    float kv[9][4];
#pragma unroll
    for (int k = 0; k < 9; ++k) {
        float4 v = *reinterpret_cast<const float4*>(Kb + (size_t)k * HWv);
        kv[k][0] = v.x; kv[k][1] = v.y; kv[k][2] = v.z; kv[k][3] = v.w;
    }

    float out[4];
#pragma unroll
    for (int p = 0; p < 4; ++p) {
        out[p] = kv[0][p] * r0[p + 1]
               + kv[1][p] * r0[p]
               + kv[2][p] * r0[p + 2]
               + kv[3][p] * rm[p + 1]
               + kv[4][p] * rm[p]
               + kv[5][p] * rm[p + 2]
               + kv[6][p] * rp[p + 1]
               + kv[7][p] * rp[p]
               + kv[8][p] * rp[p + 2];
    }

    *reinterpret_cast<float4*>(xout + (size_t)b * HWv + (size_t)y * WW + x0) =
        make_float4(out[0], out[1], out[2], out[3]);
}

// ---------------------------------------------------------------------------
extern "C" void kernel_launch(void* const* d_in, const int* in_sizes, int n_in,
                              void* d_out, int out_size, void* d_ws, size_t ws_size,
                              hipStream_t stream) {
    const float* kx   = (const float*)d_in[0];   // [4,32,480,640]
    const float* x_in = (const float*)d_in[1];   // [4,1,480,640]
    const float* Wf   = (const float*)d_in[2];   // [8,32,3,3]
    const float* bf   = (const float*)d_in[3];   // [8]
    float* out  = (float*)d_out;                 // [4,1,480,640]
    float* ws   = (float*)d_ws;

    float* Kbuf = ws;                             // 9*4*480*640 floats = 44.2 MB
    float* xbuf = ws + (size_t)9 * BB * HWv;      // 4*480*640 floats  =  4.9 MB

    // conv: 4800 blocks x 64 threads (tile 4x64, 4 px/thread)
    const int cblocks = BB * (HH / TR) * (WW / TC);   // 4800
    conv_gen<<<cblocks, 64, 0, stream>>>(kx, Wf, bf, Kbuf);

    // prop: 4 px/thread, block=256 -> 1200 blocks
    const int pthreads = BB * HH * (WW / 4);      // 307200
    const int pblocks  = pthreads / 256;          // 1200

    const float* src = x_in;
    for (int it = 0; it < 12; ++it) {
        float* dst = (it % 2 == 0) ? xbuf : out;  // it=11 (odd) -> d_out
        prop<<<pblocks, 256, 0, stream>>>(src, Kbuf, dst);
        src = dst;
    }
}